// Round 1
// baseline (67.118 us; speedup 1.0000x reference)
//
#include <hip/hip_runtime.h>
#include <math.h>

// Problem constants (from reference setup_inputs)
#define BB 512          // B
#define VV 2            // V
#define MM 1024         // M = V*B
#define DD 128          // D
#define KMAX 50
#define TOPK 15
#define NP 16           // neighbors per b, padded 15 -> 16
#define NBCOLS (BB*NP)  // 8192 padded neighbor columns
#define INV_T (1.0f/0.07f)

// ---------------- Workspace layout (floats) ----------------
// anchor : [MM][DD]          @ 0          (131072)
// a2     : [MM]              @ 131072     (1024)
// nvec   : [NBCOLS][DD]      @ 132096     (1048576)
// nn2    : [NBCOLS]          @ 1180672    (8192)
// accB   : [MM][BB]          @ 1188864    (524288)
// S      : [MM][MM]          @ 1713152    (1048576)
// loss   : [MM]              @ 2761728    (1024)
#define OFF_ANCHOR 0
#define OFF_A2     131072
#define OFF_NVEC   132096
#define OFF_NN2    1180672
#define OFF_ACCB   1188864
#define OFF_S      1713152
#define OFF_LOSS   2761728

// ---------------------------------------------------------------------------
// K1: gather anchor (transposed features) + neighbor vectors, and their norms
// grid = MM + NBCOLS blocks, 128 threads
// ---------------------------------------------------------------------------
__global__ void gather_kernel(const float* __restrict__ feat,
                              const int* __restrict__ indices,
                              const float* __restrict__ saved,
                              const int* __restrict__ rks,
                              float* __restrict__ anchor,
                              float* __restrict__ a2,
                              float* __restrict__ nvec,
                              float* __restrict__ nn2)
{
    __shared__ float sm[2];
    int blk = blockIdx.x;
    int d = threadIdx.x;          // 0..127
    float val;
    if (blk < MM) {
        int i = blk;
        int b = i & (BB - 1);
        int v = i >> 9;           // i / BB
        val = feat[(b * VV + v) * DD + d];
        anchor[i * DD + d] = val;
    } else {
        int j = blk - MM;
        int b = j >> 4;           // j / NP
        int k = j & 15;
        if (k > TOPK - 1) k = TOPK - 1;   // pad col duplicates k=14 (masked later)
        int idx = rks[indices[b] * KMAX + k];
        val = saved[idx * DD + d];
        nvec[j * DD + d] = val;
    }
    // block reduce sum of squares over 128 threads (2 waves)
    float sq = val * val;
    #pragma unroll
    for (int off = 32; off > 0; off >>= 1) sq += __shfl_down(sq, off);
    int lane = threadIdx.x & 63, w = threadIdx.x >> 6;
    if (lane == 0) sm[w] = sq;
    __syncthreads();
    if (threadIdx.x == 0) {
        float tot = sm[0] + sm[1];
        if (blk < MM) a2[blk] = tot;
        else          nn2[blk - MM] = tot;
    }
}

// ---------------------------------------------------------------------------
// K2: tiled fp32 GEMM  G = A @ Bmat^T   (A: [?][128], Bmat: [?][128])
// BM=BN=64, BK=32, 256 threads, 4x4 micro-tile.
// FUSED=true : epilogue turns dots into f(dist), reduces groups of 16 padded
//              k-columns into accB[i][b]   (grid 16 x 128, Bmat = nvec)
// FUSED=false: stores raw dots into S (grid 16 x 16, Bmat = anchor)
// ---------------------------------------------------------------------------
#define PITCH 68

template<bool FUSED>
__global__ __launch_bounds__(256) void gemm_kernel(
    const float* __restrict__ A, const float* __restrict__ Bmat,
    const float* __restrict__ a2, const float* __restrict__ nn2,
    float* __restrict__ out)
{
    __shared__ float As[32][PITCH];
    __shared__ float Bs[32][PITCH];
    const int tid = threadIdx.x;
    const int tx = tid & 15;
    const int ty = tid >> 4;
    const int i0 = blockIdx.x * 64;
    const int j0 = blockIdx.y * 64;

    float acc[4][4] = {};

    for (int kc = 0; kc < DD; kc += 32) {
        #pragma unroll
        for (int it = 0; it < 2; ++it) {
            int p = it * 256 + tid;
            int row = p >> 3;     // 0..63
            int k4 = p & 7;       // 0..7 (float4 index within 32-k chunk)
            float4 va = *(const float4*)&A[(i0 + row) * DD + kc + k4 * 4];
            float4 vb = *(const float4*)&Bmat[(j0 + row) * DD + kc + k4 * 4];
            As[k4 * 4 + 0][row] = va.x;
            As[k4 * 4 + 1][row] = va.y;
            As[k4 * 4 + 2][row] = va.z;
            As[k4 * 4 + 3][row] = va.w;
            Bs[k4 * 4 + 0][row] = vb.x;
            Bs[k4 * 4 + 1][row] = vb.y;
            Bs[k4 * 4 + 2][row] = vb.z;
            Bs[k4 * 4 + 3][row] = vb.w;
        }
        __syncthreads();
        #pragma unroll
        for (int kk = 0; kk < 32; ++kk) {
            float4 a4 = *(const float4*)&As[kk][ty * 4];
            float4 b4 = *(const float4*)&Bs[kk][tx * 4];
            float av[4] = {a4.x, a4.y, a4.z, a4.w};
            float bv[4] = {b4.x, b4.y, b4.z, b4.w};
            #pragma unroll
            for (int ri = 0; ri < 4; ++ri)
                #pragma unroll
                for (int ci = 0; ci < 4; ++ci)
                    acc[ri][ci] += av[ri] * bv[ci];
        }
        __syncthreads();
    }

    if (FUSED) {
        // cols c = j0 + tx*4 + ci ; b = c/16 ; k = c%16 = (tx&3)*4 + ci
        const int b0 = (j0 >> 4) + (tx >> 2);
        #pragma unroll
        for (int ri = 0; ri < 4; ++ri) {
            int i = i0 + ty * 4 + ri;
            float a2i = a2[i];
            float s = 0.f;
            #pragma unroll
            for (int ci = 0; ci < 4; ++ci) {
                int c = j0 + tx * 4 + ci;
                float g = acc[ri][ci];
                float sq = fmaxf(a2i + nn2[c] - 2.f * g, 0.f);
                float dist = sqrtf(sq);
                float f = (1.f + 1.f / (1.f + dist)) * INV_T;
                if ((c & 15) == 15) f = 0.f;   // mask the pad column
                s += f;
            }
            // reduce over the 4 threads covering the 16 k's of this b
            s += __shfl_xor(s, 1);
            s += __shfl_xor(s, 2);
            if ((tx & 3) == 0) out[i * BB + b0] = s * (1.0f / TOPK);
        }
    } else {
        #pragma unroll
        for (int ri = 0; ri < 4; ++ri) {
            int i = i0 + ty * 4 + ri;
            float4 v = make_float4(acc[ri][0], acc[ri][1], acc[ri][2], acc[ri][3]);
            *(float4*)&out[i * MM + j0 + tx * 4] = v;
        }
    }
}

// ---------------------------------------------------------------------------
// K3: per-row softmax-style loss. One block (256 threads) per row i.
// ---------------------------------------------------------------------------
__global__ __launch_bounds__(256) void row_kernel(const float* __restrict__ S,
                                                  const float* __restrict__ a2,
                                                  const float* __restrict__ accB,
                                                  float* __restrict__ loss)
{
    __shared__ float redmax[4];
    __shared__ float redsum[4];
    __shared__ float smpos;
    const int i = blockIdx.x;
    const int tid = threadIdx.x;
    const int lane = tid & 63, w = tid >> 6;
    const int ib = i & (BB - 1);
    const int pos = i ^ BB;       // (i + B) mod M
    const float a2i = a2[i];

    float ls[4];
    float mymax = -1e30f;
    #pragma unroll
    for (int q = 0; q < 4; ++q) {
        int j = tid + q * 256;
        float s = S[i * MM + j];
        float sq = fmaxf(a2i + a2[j] - 2.f * s, 0.f);
        float d0 = sqrtf(sq);
        float adc = (1.f + 1.f / (1.f + d0)) * INV_T;
        float aij = accB[i * BB + (j & (BB - 1))];
        float aji = accB[j * BB + ib];
        ls[q] = sqrtf(aij * aij + aji * aji + adc * adc);
        mymax = fmaxf(mymax, ls[q]);
        if (j == pos) smpos = ls[q];
    }
    // block max
    float m = mymax;
    #pragma unroll
    for (int off = 32; off > 0; off >>= 1) m = fmaxf(m, __shfl_xor(m, off));
    if (lane == 0) redmax[w] = m;
    __syncthreads();
    m = fmaxf(fmaxf(redmax[0], redmax[1]), fmaxf(redmax[2], redmax[3]));

    // exp-sum excluding diagonal
    float e = 0.f;
    #pragma unroll
    for (int q = 0; q < 4; ++q) {
        int j = tid + q * 256;
        if (j != i) e += expf(ls[q] - m);
    }
    #pragma unroll
    for (int off = 32; off > 0; off >>= 1) e += __shfl_xor(e, off);
    if (lane == 0) redsum[w] = e;
    __syncthreads();
    if (tid == 0) {
        float esum = redsum[0] + redsum[1] + redsum[2] + redsum[3];
        loss[i] = logf(esum) - (smpos - m);
    }
}

// ---------------------------------------------------------------------------
// K4: mean of 1024 losses -> scalar output
// ---------------------------------------------------------------------------
__global__ void final_kernel(const float* __restrict__ loss, float* __restrict__ out)
{
    __shared__ float red[4];
    int tid = threadIdx.x;
    float s = 0.f;
    #pragma unroll
    for (int q = 0; q < 4; ++q) s += loss[tid + q * 256];
    #pragma unroll
    for (int off = 32; off > 0; off >>= 1) s += __shfl_xor(s, off);
    int lane = tid & 63, w = tid >> 6;
    if (lane == 0) red[w] = s;
    __syncthreads();
    if (tid == 0) out[0] = (red[0] + red[1] + red[2] + red[3]) * (1.0f / MM);
}

// ---------------------------------------------------------------------------
extern "C" void kernel_launch(void* const* d_in, const int* in_sizes, int n_in,
                              void* d_out, int out_size, void* d_ws, size_t ws_size,
                              hipStream_t stream)
{
    const float* feat    = (const float*)d_in[0];  // (512, 2, 128) f32
    const int*   indices = (const int*)  d_in[1];  // (512,) i32
    const float* saved   = (const float*)d_in[2];  // (100000, 128) f32
    const int*   rks     = (const int*)  d_in[3];  // (100000, 50) i32
    float* out = (float*)d_out;

    float* ws     = (float*)d_ws;
    float* anchor = ws + OFF_ANCHOR;
    float* a2     = ws + OFF_A2;
    float* nvec   = ws + OFF_NVEC;
    float* nn2    = ws + OFF_NN2;
    float* accB   = ws + OFF_ACCB;
    float* S      = ws + OFF_S;
    float* loss   = ws + OFF_LOSS;

    // K1: gather + norms
    gather_kernel<<<MM + NBCOLS, 128, 0, stream>>>(feat, indices, saved, rks,
                                                   anchor, a2, nvec, nn2);
    // K2a: fused distance GEMM -> accB  (1024 x 8192 padded cols)
    gemm_kernel<true><<<dim3(MM / 64, NBCOLS / 64), 256, 0, stream>>>(
        anchor, nvec, a2, nn2, accB);
    // K2b: plain GEMM -> S = anchor @ anchor^T
    gemm_kernel<false><<<dim3(MM / 64, MM / 64), 256, 0, stream>>>(
        anchor, anchor, a2, nn2, S);
    // K3: per-row loss
    row_kernel<<<MM, 256, 0, stream>>>(S, a2, accB, loss);
    // K4: mean
    final_kernel<<<1, 256, 0, stream>>>(loss, out);
}

// Round 2
// 50.556 us; speedup vs baseline: 1.3276x; 1.3276x over previous
//
#include <hip/hip_runtime.h>
#include <hip/hip_bf16.h>
#include <math.h>

// Problem constants (from reference setup_inputs)
#define BB 512          // B
#define VV 2            // V
#define MM 1024         // M = V*B
#define DD 128          // D
#define KMAX 50
#define TOPK 15
#define NP 16           // neighbors per b, padded 15 -> 16
#define NBCOLS (BB*NP)  // 8192 padded neighbor columns
#define INV_T (1.0f/0.07f)

// ---------------- Workspace layout (byte offsets) ----------------
#define OFFB_ANCH 0            // __hip_bfloat16 [MM][DD]      262144 B
#define OFFB_NVEC 262144       // __hip_bfloat16 [NBCOLS][DD] 2097152 B
#define OFFB_A2   2359296      // float [MM]                     4096 B
#define OFFB_NN2  2363392      // float [NBCOLS]                32768 B
#define OFFB_ACCB 2396160      // float [MM][BB]              2097152 B
#define OFFB_S    4493312      // float [MM][MM]              4194304 B
#define OFFB_LOSS 8687616      // float [MM]                     4096 B

typedef __attribute__((ext_vector_type(8))) short bf16x8;
typedef __attribute__((ext_vector_type(4))) float f32x4;

// ---------------------------------------------------------------------------
// K1: gather anchor (transposed features) + neighbor vectors (as bf16),
//     plus fp32 squared norms.  grid = MM + NBCOLS blocks, 128 threads.
// ---------------------------------------------------------------------------
__global__ void gather_kernel(const float* __restrict__ feat,
                              const int* __restrict__ indices,
                              const float* __restrict__ saved,
                              const int* __restrict__ rks,
                              __hip_bfloat16* __restrict__ anchor,
                              float* __restrict__ a2,
                              __hip_bfloat16* __restrict__ nvec,
                              float* __restrict__ nn2)
{
    __shared__ float sm[2];
    int blk = blockIdx.x;
    int d = threadIdx.x;          // 0..127
    float val;
    if (blk < MM) {
        int i = blk;
        int b = i & (BB - 1);
        int v = i >> 9;           // i / BB
        val = feat[(b * VV + v) * DD + d];
        anchor[i * DD + d] = __float2bfloat16(val);
    } else {
        int j = blk - MM;
        int b = j >> 4;           // j / NP
        int k = j & 15;
        if (k > TOPK - 1) k = TOPK - 1;   // pad col duplicates k=14 (masked later)
        int idx = rks[indices[b] * KMAX + k];
        val = saved[idx * DD + d];
        nvec[j * DD + d] = __float2bfloat16(val);
    }
    // block reduce sum of squares over 128 threads (2 waves)
    float sq = val * val;
    #pragma unroll
    for (int off = 32; off > 0; off >>= 1) sq += __shfl_down(sq, off);
    int lane = threadIdx.x & 63, w = threadIdx.x >> 6;
    if (lane == 0) sm[w] = sq;
    __syncthreads();
    if (threadIdx.x == 0) {
        float tot = sm[0] + sm[1];
        if (blk < MM) a2[blk] = tot;
        else          nn2[blk - MM] = tot;
    }
}

// ---------------------------------------------------------------------------
// K2: bf16 MFMA GEMM  G = A @ Bmat^T  (A: [?][128] bf16, Bmat: [?][128] bf16)
// Block = 256 thr = 4 waves (2x2). Block tile 64x128, wave tile 32x64.
// No LDS: fragments loaded straight from L2-resident bf16 buffers.
// mfma_f32_16x16x32_bf16: A/B frag = lane&15 -> row, (lane>>4)*8 -> k chunk;
// C/D: col = lane&15, row = (lane>>4)*4 + reg  [verified layout].
// FUSED=true : epilogue f(dist) + reduce 16 padded k-cols -> accB[i][b]
// FUSED=false: raw dots -> S
// ---------------------------------------------------------------------------
template<bool FUSED>
__global__ __launch_bounds__(256) void mfma_gemm(
    const __hip_bfloat16* __restrict__ A, const __hip_bfloat16* __restrict__ Bm,
    const float* __restrict__ a2, const float* __restrict__ nn2,
    float* __restrict__ out)
{
    const int tid  = threadIdx.x;
    const int lane = tid & 63;
    const int wid  = tid >> 6;
    const int m0 = blockIdx.x * 64 + (wid >> 1) * 32;
    const int j0 = blockIdx.y * 128 + (wid & 1) * 64;
    const int lr = lane & 15;           // row (A) / col (B,C)
    const int lk = (lane >> 4) * 8;     // k sub-offset within 32-chunk

    f32x4 acc[2][4];
    #pragma unroll
    for (int a = 0; a < 2; ++a)
        #pragma unroll
        for (int b = 0; b < 4; ++b) acc[a][b] = (f32x4){0.f, 0.f, 0.f, 0.f};

    #pragma unroll
    for (int kc = 0; kc < DD; kc += 32) {
        bf16x8 af[2], bfr[4];
        #pragma unroll
        for (int tm = 0; tm < 2; ++tm)
            af[tm] = *(const bf16x8*)&A[(m0 + tm * 16 + lr) * DD + kc + lk];
        #pragma unroll
        for (int tn = 0; tn < 4; ++tn)
            bfr[tn] = *(const bf16x8*)&Bm[(j0 + tn * 16 + lr) * DD + kc + lk];
        #pragma unroll
        for (int tm = 0; tm < 2; ++tm)
            #pragma unroll
            for (int tn = 0; tn < 4; ++tn)
                acc[tm][tn] = __builtin_amdgcn_mfma_f32_16x16x32_bf16(
                    af[tm], bfr[tn], acc[tm][tn], 0, 0, 0);
    }

    const int rbase = (lane >> 4) * 4;
    if (FUSED) {
        #pragma unroll
        for (int tm = 0; tm < 2; ++tm) {
            float a2v[4];
            #pragma unroll
            for (int r = 0; r < 4; ++r) a2v[r] = a2[m0 + tm * 16 + rbase + r];
            #pragma unroll
            for (int tn = 0; tn < 4; ++tn) {
                int c = j0 + tn * 16 + lr;
                float nn2c = nn2[c];
                int b = c >> 4;
                #pragma unroll
                for (int r = 0; r < 4; ++r) {
                    float g = acc[tm][tn][r];
                    float sq = fmaxf(a2v[r] + nn2c - 2.f * g, 0.f);
                    float dist = sqrtf(sq);
                    float f = (1.f + 1.f / (1.f + dist)) * INV_T;
                    if (lr == 15) f = 0.f;          // mask pad column
                    f += __shfl_xor(f, 1);
                    f += __shfl_xor(f, 2);
                    f += __shfl_xor(f, 4);
                    f += __shfl_xor(f, 8);
                    if (lr == 0)
                        out[(m0 + tm * 16 + rbase + r) * BB + b] = f * (1.0f / TOPK);
                }
            }
        }
    } else {
        #pragma unroll
        for (int tm = 0; tm < 2; ++tm)
            #pragma unroll
            for (int tn = 0; tn < 4; ++tn)
                #pragma unroll
                for (int r = 0; r < 4; ++r)
                    out[(m0 + tm * 16 + rbase + r) * MM + j0 + tn * 16 + lr] =
                        acc[tm][tn][r];
    }
}

// ---------------------------------------------------------------------------
// K3: per-row softmax-style loss. One block (256 threads) per row i.
// ---------------------------------------------------------------------------
__global__ __launch_bounds__(256) void row_kernel(const float* __restrict__ S,
                                                  const float* __restrict__ a2,
                                                  const float* __restrict__ accB,
                                                  float* __restrict__ loss)
{
    __shared__ float redmax[4];
    __shared__ float redsum[4];
    __shared__ float smpos;
    const int i = blockIdx.x;
    const int tid = threadIdx.x;
    const int lane = tid & 63, w = tid >> 6;
    const int ib = i & (BB - 1);
    const int pos = i ^ BB;       // the single positive pair
    const float a2i = a2[i];

    float ls[4];
    float mymax = -1e30f;
    #pragma unroll
    for (int q = 0; q < 4; ++q) {
        int j = tid + q * 256;
        float s = S[i * MM + j];
        float sq = fmaxf(a2i + a2[j] - 2.f * s, 0.f);
        float d0 = sqrtf(sq);
        float adc = (1.f + 1.f / (1.f + d0)) * INV_T;
        float aij = accB[i * BB + (j & (BB - 1))];
        float aji = accB[j * BB + ib];
        ls[q] = sqrtf(aij * aij + aji * aji + adc * adc);
        mymax = fmaxf(mymax, ls[q]);
        if (j == pos) smpos = ls[q];
    }
    float m = mymax;
    #pragma unroll
    for (int off = 32; off > 0; off >>= 1) m = fmaxf(m, __shfl_xor(m, off));
    if (lane == 0) redmax[w] = m;
    __syncthreads();
    m = fmaxf(fmaxf(redmax[0], redmax[1]), fmaxf(redmax[2], redmax[3]));

    float e = 0.f;
    #pragma unroll
    for (int q = 0; q < 4; ++q) {
        int j = tid + q * 256;
        if (j != i) e += expf(ls[q] - m);
    }
    #pragma unroll
    for (int off = 32; off > 0; off >>= 1) e += __shfl_xor(e, off);
    if (lane == 0) redsum[w] = e;
    __syncthreads();
    if (tid == 0) {
        float esum = redsum[0] + redsum[1] + redsum[2] + redsum[3];
        loss[i] = logf(esum) - (smpos - m);
    }
}

// ---------------------------------------------------------------------------
// K4: mean of 1024 losses -> scalar output
// ---------------------------------------------------------------------------
__global__ void final_kernel(const float* __restrict__ loss, float* __restrict__ out)
{
    __shared__ float red[4];
    int tid = threadIdx.x;
    float s = 0.f;
    #pragma unroll
    for (int q = 0; q < 4; ++q) s += loss[tid + q * 256];
    #pragma unroll
    for (int off = 32; off > 0; off >>= 1) s += __shfl_xor(s, off);
    int lane = tid & 63, w = tid >> 6;
    if (lane == 0) red[w] = s;
    __syncthreads();
    if (tid == 0) out[0] = (red[0] + red[1] + red[2] + red[3]) * (1.0f / MM);
}

// ---------------------------------------------------------------------------
extern "C" void kernel_launch(void* const* d_in, const int* in_sizes, int n_in,
                              void* d_out, int out_size, void* d_ws, size_t ws_size,
                              hipStream_t stream)
{
    const float* feat    = (const float*)d_in[0];  // (512, 2, 128) f32
    const int*   indices = (const int*)  d_in[1];  // (512,) i32
    const float* saved   = (const float*)d_in[2];  // (100000, 128) f32
    const int*   rks     = (const int*)  d_in[3];  // (100000, 50) i32
    float* out = (float*)d_out;

    char* w = (char*)d_ws;
    __hip_bfloat16* anch_bf = (__hip_bfloat16*)(w + OFFB_ANCH);
    __hip_bfloat16* nvec_bf = (__hip_bfloat16*)(w + OFFB_NVEC);
    float* a2   = (float*)(w + OFFB_A2);
    float* nn2  = (float*)(w + OFFB_NN2);
    float* accB = (float*)(w + OFFB_ACCB);
    float* S    = (float*)(w + OFFB_S);
    float* loss = (float*)(w + OFFB_LOSS);

    // K1: gather + bf16 convert + norms
    gather_kernel<<<MM + NBCOLS, 128, 0, stream>>>(feat, indices, saved, rks,
                                                   anch_bf, a2, nvec_bf, nn2);
    // K2a: fused distance MFMA-GEMM -> accB   (1024 x 8192 padded cols)
    mfma_gemm<true><<<dim3(MM / 64, NBCOLS / 128), 256, 0, stream>>>(
        anch_bf, nvec_bf, a2, nn2, accB);
    // K2b: plain MFMA-GEMM -> S = anchor @ anchor^T
    mfma_gemm<false><<<dim3(MM / 64, MM / 128), 256, 0, stream>>>(
        anch_bf, anch_bf, a2, nn2, S);
    // K3: per-row loss
    row_kernel<<<MM, 256, 0, stream>>>(S, a2, accB, loss);
    // K4: mean
    final_kernel<<<1, 256, 0, stream>>>(loss, out);
}

// Round 3
// 44.780 us; speedup vs baseline: 1.4988x; 1.1290x over previous
//
#include <hip/hip_runtime.h>
#include <hip/hip_bf16.h>
#include <math.h>

// Problem constants
#define BB 512          // B
#define VV 2            // V
#define MM 1024         // M = V*B
#define DD 128          // D
#define KMAX 50
#define TOPK 15
#define NP 16           // neighbors per b, padded 15 -> 16
#define NBROWS (BB*NP)  // 8192 neighbor rows (GEMM M-dim)
#define INV_T (1.0f/0.07f)

// ---------------- Workspace layout (byte offsets) ----------------
#define OFFB_ANCH 0                          // bf16 [MM][DD]      256 KB
#define OFFB_NVEC (256*1024)                 // bf16 [NBROWS][DD]    2 MB
#define OFFB_A2   (OFFB_NVEC + 2*1024*1024)  // f32  [MM]            4 KB
#define OFFB_NN2  (OFFB_A2 + 4*1024)         // f32  [NBROWS]       32 KB
#define OFFB_ACCT (OFFB_NN2 + 32*1024)       // f32  [BB][MM]        2 MB  (accT[b][i])
#define OFFB_ADC  (OFFB_ACCT + 2*1024*1024)  // f32  [MM][MM]        4 MB  (adc_orig)
#define OFFB_LOSS (OFFB_ADC + 4*1024*1024)   // f32  [MM]            4 KB

typedef __attribute__((ext_vector_type(8))) short bf16x8;
typedef __attribute__((ext_vector_type(4))) float f32x4;

// ---------------------------------------------------------------------------
// K1: gather (wave per row): anchor = transposed features -> bf16,
//     nvec = gathered neighbor rows -> bf16, plus fp32 squared norms.
// grid = (MM+NBROWS)/4 blocks of 256 threads (4 waves, 1 row each).
// ---------------------------------------------------------------------------
__global__ __launch_bounds__(256) void gather2(
    const float* __restrict__ feat, const int* __restrict__ indices,
    const float* __restrict__ saved, const int* __restrict__ rks,
    __hip_bfloat16* __restrict__ anchor, float* __restrict__ a2,
    __hip_bfloat16* __restrict__ nvec, float* __restrict__ nn2)
{
    const int row  = blockIdx.x * 4 + (threadIdx.x >> 6);
    const int lane = threadIdx.x & 63;
    float2 v;
    __hip_bfloat16* dst;
    if (row < MM) {
        int b = row & (BB - 1);
        int vv = row >> 9;
        v = *(const float2*)&feat[(b * VV + vv) * DD + lane * 2];
        dst = anchor + row * DD;
    } else {
        int j = row - MM;
        int b = j >> 4;
        int k = j & 15; if (k > TOPK - 1) k = TOPK - 1;  // pad col dup (masked)
        int idx = rks[indices[b] * KMAX + k];
        v = *(const float2*)&saved[idx * DD + lane * 2];
        dst = nvec + (size_t)j * DD;
    }
    union { __hip_bfloat16 h[2]; unsigned u; } pk;
    pk.h[0] = __float2bfloat16(v.x);
    pk.h[1] = __float2bfloat16(v.y);
    *(unsigned*)(dst + lane * 2) = pk.u;

    float sq = v.x * v.x + v.y * v.y;
    #pragma unroll
    for (int off = 32; off > 0; off >>= 1) sq += __shfl_xor(sq, off);
    if (lane == 0) {
        if (row < MM) a2[row] = sq;
        else          nn2[row - MM] = sq;
    }
}

// ---------------------------------------------------------------------------
// K2: merged MFMA GEMM.
//   bx <  128 : FUSED  G = nvec @ anchor^T (8192 x 1024), epilogue reduces the
//               16 k-rows of each C fragment (3 adds + 2 shfl) -> accT[b][i],
//               coalesced 64B stores.
//   bx >= 128 : S path G = anchor @ anchor^T (1024 x 1024), epilogue stores
//               adc_orig[i][j] directly (coalesced).
// Block 256 thr = 4 waves (2x2), block tile 64 x 128, wave tile 32 x 64.
// C layout of mfma_f32_16x16x32_bf16: col = lane&15, row = (lane>>4)*4 + reg.
// ---------------------------------------------------------------------------
__global__ __launch_bounds__(256) void dist_gemm(
    const __hip_bfloat16* __restrict__ anchor,
    const __hip_bfloat16* __restrict__ nvec,
    const float* __restrict__ a2, const float* __restrict__ nn2,
    float* __restrict__ accT, float* __restrict__ adcM)
{
    const int tid = threadIdx.x;
    const int lane = tid & 63;
    const int wid = tid >> 6;
    const int lr = lane & 15;
    const int lg = lane >> 4;
    const bool isS = (blockIdx.x >= 128);
    const int bx = isS ? (blockIdx.x - 128) : blockIdx.x;
    const int m0 = bx * 64 + (wid >> 1) * 32;              // row base (nvec or anchor)
    const int j0 = blockIdx.y * 128 + (wid & 1) * 64;      // anchor-col base
    const __hip_bfloat16* __restrict__ Arows = isS ? anchor : nvec;

    f32x4 acc[2][4];
    #pragma unroll
    for (int a = 0; a < 2; ++a)
        #pragma unroll
        for (int b = 0; b < 4; ++b) acc[a][b] = (f32x4){0.f, 0.f, 0.f, 0.f};

    #pragma unroll
    for (int kc = 0; kc < DD; kc += 32) {
        bf16x8 af[2], bfr[4];
        #pragma unroll
        for (int tm = 0; tm < 2; ++tm)
            af[tm] = *(const bf16x8*)&Arows[(size_t)(m0 + tm * 16 + lr) * DD + kc + lg * 8];
        #pragma unroll
        for (int tn = 0; tn < 4; ++tn)
            bfr[tn] = *(const bf16x8*)&anchor[(size_t)(j0 + tn * 16 + lr) * DD + kc + lg * 8];
        #pragma unroll
        for (int tm = 0; tm < 2; ++tm)
            #pragma unroll
            for (int tn = 0; tn < 4; ++tn)
                acc[tm][tn] = __builtin_amdgcn_mfma_f32_16x16x32_bf16(
                    af[tm], bfr[tn], acc[tm][tn], 0, 0, 0);
    }

    if (!isS) {
        #pragma unroll
        for (int tm = 0; tm < 2; ++tm) {
            const int cbase = m0 + tm * 16 + lg * 4;       // neighbor row of acc[r]
            const float4 nnv = *(const float4*)&nn2[cbase];
            const float nnr[4] = {nnv.x, nnv.y, nnv.z, nnv.w};
            const int b = (m0 + tm * 16) >> 4;             // b group of this fragment
            #pragma unroll
            for (int tn = 0; tn < 4; ++tn) {
                const int j = j0 + tn * 16 + lr;
                const float a2j = a2[j];
                float s = 0.f;
                #pragma unroll
                for (int r = 0; r < 4; ++r) {
                    float g = acc[tm][tn][r];
                    float sq = fmaxf(fmaf(-2.f, g, a2j + nnr[r]), 0.f);
                    float d = __builtin_amdgcn_sqrtf(sq);
                    float f = fmaf(__builtin_amdgcn_rcpf(1.f + d), INV_T, INV_T);
                    if (lg == 3 && r == 3) f = 0.f;        // k == 15 pad row
                    s += f;
                }
                s += __shfl_xor(s, 16);
                s += __shfl_xor(s, 32);                    // sum over 16 k-rows
                if (lane < 16)
                    accT[(size_t)b * MM + j0 + tn * 16 + lane] = s * (1.0f / TOPK);
            }
        }
    } else {
        #pragma unroll
        for (int tm = 0; tm < 2; ++tm) {
            const float4 a2v = *(const float4*)&a2[m0 + tm * 16 + lg * 4];
            const float a2r[4] = {a2v.x, a2v.y, a2v.z, a2v.w};
            #pragma unroll
            for (int tn = 0; tn < 4; ++tn) {
                const int j = j0 + tn * 16 + lr;
                const float a2j = a2[j];
                #pragma unroll
                for (int r = 0; r < 4; ++r) {
                    float g = acc[tm][tn][r];
                    float sq = fmaxf(fmaf(-2.f, g, a2j + a2r[r]), 0.f);
                    float d = __builtin_amdgcn_sqrtf(sq);
                    float adc = fmaf(__builtin_amdgcn_rcpf(1.f + d), INV_T, INV_T);
                    adcM[(size_t)(m0 + tm * 16 + lg * 4 + r) * MM + j] = adc;
                }
            }
        }
    }
}

// ---------------------------------------------------------------------------
// K3: loss for 4 rows per block (256 blocks x 256 threads).
// ls[i][j] = sqrt(accT[j&511][i]^2 + accT[i&511][j]^2 + adc[i][j]^2)
// loss[i] = log(sum_{j!=i} exp(ls-m)) - (ls[pos]-m),  pos = i ^ 512.
// ---------------------------------------------------------------------------
__global__ __launch_bounds__(256) void row4_kernel(
    const float* __restrict__ adcM, const float* __restrict__ accT,
    float* __restrict__ loss)
{
    __shared__ float redmax[4][4];
    __shared__ float redsum[4][4];
    __shared__ float lsposS[4];
    const int i0 = blockIdx.x * 4;
    const int tid = threadIdx.x;
    const int lane = tid & 63, w = tid >> 6;
    const int pos0 = i0 ^ BB;

    float ls[4][4];
    float mx[4] = {-1e30f, -1e30f, -1e30f, -1e30f};
    #pragma unroll
    for (int q = 0; q < 4; ++q) {
        const int j = tid + q * 256;
        const float4 av = *(const float4*)&accT[(size_t)(j & (BB - 1)) * MM + i0];
        const float aij[4] = {av.x, av.y, av.z, av.w};
        #pragma unroll
        for (int r = 0; r < 4; ++r) {
            float aji = accT[(size_t)((i0 + r) & (BB - 1)) * MM + j];
            float adc = adcM[(size_t)(i0 + r) * MM + j];
            float v = __builtin_amdgcn_sqrtf(aij[r] * aij[r] + aji * aji + adc * adc);
            ls[q][r] = v;
            mx[r] = fmaxf(mx[r], v);
            if (j == pos0 + r) lsposS[r] = v;
        }
    }
    #pragma unroll
    for (int r = 0; r < 4; ++r) {
        float m = mx[r];
        #pragma unroll
        for (int off = 32; off > 0; off >>= 1) m = fmaxf(m, __shfl_xor(m, off));
        if (lane == 0) redmax[r][w] = m;
    }
    __syncthreads();
    float m4[4];
    #pragma unroll
    for (int r = 0; r < 4; ++r)
        m4[r] = fmaxf(fmaxf(redmax[r][0], redmax[r][1]),
                      fmaxf(redmax[r][2], redmax[r][3]));

    float es[4] = {0.f, 0.f, 0.f, 0.f};
    #pragma unroll
    for (int q = 0; q < 4; ++q) {
        const int j = tid + q * 256;
        #pragma unroll
        for (int r = 0; r < 4; ++r)
            if (j != i0 + r) es[r] += __expf(ls[q][r] - m4[r]);
    }
    #pragma unroll
    for (int r = 0; r < 4; ++r) {
        float e = es[r];
        #pragma unroll
        for (int off = 32; off > 0; off >>= 1) e += __shfl_xor(e, off);
        if (lane == 0) redsum[r][w] = e;
    }
    __syncthreads();
    if (tid < 4) {
        float esum = redsum[tid][0] + redsum[tid][1] + redsum[tid][2] + redsum[tid][3];
        loss[i0 + tid] = __logf(esum) - (lsposS[tid] - m4[tid]);
    }
}

// ---------------------------------------------------------------------------
// K4: mean of 1024 losses -> scalar output
// ---------------------------------------------------------------------------
__global__ void final_kernel(const float* __restrict__ loss, float* __restrict__ out)
{
    __shared__ float red[4];
    int tid = threadIdx.x;
    float s = 0.f;
    #pragma unroll
    for (int q = 0; q < 4; ++q) s += loss[tid + q * 256];
    #pragma unroll
    for (int off = 32; off > 0; off >>= 1) s += __shfl_xor(s, off);
    int lane = tid & 63, w = tid >> 6;
    if (lane == 0) red[w] = s;
    __syncthreads();
    if (tid == 0) out[0] = (red[0] + red[1] + red[2] + red[3]) * (1.0f / MM);
}

// ---------------------------------------------------------------------------
extern "C" void kernel_launch(void* const* d_in, const int* in_sizes, int n_in,
                              void* d_out, int out_size, void* d_ws, size_t ws_size,
                              hipStream_t stream)
{
    const float* feat    = (const float*)d_in[0];  // (512, 2, 128) f32
    const int*   indices = (const int*)  d_in[1];  // (512,) i32
    const float* saved   = (const float*)d_in[2];  // (100000, 128) f32
    const int*   rks     = (const int*)  d_in[3];  // (100000, 50) i32
    float* out = (float*)d_out;

    char* w = (char*)d_ws;
    __hip_bfloat16* anch_bf = (__hip_bfloat16*)(w + OFFB_ANCH);
    __hip_bfloat16* nvec_bf = (__hip_bfloat16*)(w + OFFB_NVEC);
    float* a2   = (float*)(w + OFFB_A2);
    float* nn2  = (float*)(w + OFFB_NN2);
    float* accT = (float*)(w + OFFB_ACCT);
    float* adcM = (float*)(w + OFFB_ADC);
    float* loss = (float*)(w + OFFB_LOSS);

    // K1: gather + bf16 convert + norms (wave per row)
    gather2<<<(MM + NBROWS) / 4, 256, 0, stream>>>(feat, indices, saved, rks,
                                                   anch_bf, a2, nvec_bf, nn2);
    // K2: merged MFMA GEMMs: fused distance->accT (bx<128), adc_orig (bx>=128)
    dist_gemm<<<dim3(128 + MM / 64, 8), 256, 0, stream>>>(
        anch_bf, nvec_bf, a2, nn2, accT, adcM);
    // K3: per-row loss, 4 rows/block
    row4_kernel<<<MM / 4, 256, 0, stream>>>(adcM, accT, loss);
    // K4: mean
    final_kernel<<<1, 256, 0, stream>>>(loss, out);
}